// Round 14
// baseline (112.097 us; speedup 1.0000x reference)
//
#include <hip/hip_runtime.h>
#include <hip/hip_bf16.h>

// Quantized 3x3 conv via int8 implicit GEMM — barrier-free K-loop with
// register-double-buffered B (global->reg), A resident in LDS.
// B=32, Cin=128, Cout=256, H=W=56, pad=1. M=(b,h,w64), N=256, K=9x128.
//
// (x-xz)(w-wz) = xi*wi + (128-wz)*xi,  xi=x-128 (int8), wi=w-128 (int8);
// acc = i8gemm + (128-wz)*S,  S = window-sum of xi (pads contribute 0).
//
// xpi8 blob per (b,hh), 8KB: byte(w,c) = w*128 + (c ^ ((w&7)<<4))  (A swizzle,
// staged linearly by global_load_lds, read with the same XOR — rule #21).
// wt layout (wave-contiguous panels, B read direct global->reg):
//   byte(s,wn,fn,l15,lg) = s*16384 + wn*4096 + fn*1024 + l15*64 + lg*16,
//   n = wn*64+fn*16+l15, kl = lg*16+j, cin = (s&1)*64+kl, r = s>>1.
//   Each per-fn load instruction covers one dense 1KB range (16 full lines).
//
// conv: 256 thr / 4 waves (1m x 4n), tile 64m(1 h-row) x 256n; per-wave
// 64x64 transposed-D (R13-proven coalesced epilogue). K-loop: NO barriers;
// step s issues step s+1's B loads (bnext), consumes bcur -> load-use
// distance = 1 full step >> L2 latency. 3 blocks/CU, waves drift freely.

typedef __attribute__((ext_vector_type(4))) int   i32x4;
typedef __attribute__((ext_vector_type(4))) float f32x4;

#define WTI8_BYTES (18 * 16384)            // 294,912
#define XPI8_BYTES (32 * 58 * 8192)        // 15,204,352

__device__ __forceinline__ void gload_lds16(const void* g, void* l) {
    __builtin_amdgcn_global_load_lds(
        (const __attribute__((address_space(1))) void*)g,
        (__attribute__((address_space(3))) void*)l, 16, 0, 0);
}

// ---- weight prep: w[cout][cin][3][3] - 128 -> wave-contiguous panels ----
__global__ void wprep_kernel(const float* __restrict__ w, char* __restrict__ wt) {
    int cidx = blockIdx.x * 256 + threadIdx.x;   // 16B chunk id, < 18432
    int byte0 = cidx * 16;
    int s   = byte0 >> 14;                       // 0..17
    int wnn = (byte0 >> 12) & 3;
    int fn  = (byte0 >> 10) & 3;
    int l15 = (byte0 >> 6) & 15;
    int lg  = (byte0 >> 4) & 3;
    int n = wnn * 64 + fn * 16 + l15;
    int r = s >> 1, ch = s & 1;
    union { char c[16]; i32x4 v; } u;
#pragma unroll
    for (int j = 0; j < 16; ++j) {
        int cin = ch * 64 + lg * 16 + j;
        u.c[j] = (char)((int)w[(size_t)n * 1152 + cin * 9 + r] - 128);
    }
    *(i32x4*)(wt + byte0) = u.v;
}

// ---- x prep: coalesced NCHW read -> swizzled padded NHWC int8 + colsum ----
__global__ void xprep_kernel(const float* __restrict__ x, const float* __restrict__ xzp,
                             char* __restrict__ xpi8, int* __restrict__ colsum) {
    int bhh = blockIdx.x;                        // b*58 + hh
    int b = bhh / 58, hh = bhh % 58;
    int tid = threadIdx.x;
    char* blob = xpi8 + (size_t)bhh * 8192;
    int w  = tid & 63;                           // padded col (lane = w: coalesced)
    int cq = tid >> 6;                           // 0..3, 32 cin each
    __shared__ int ps[4][64];
    if (hh == 0 || hh == 57) {
        i32x4 z = {0, 0, 0, 0};
        *(i32x4*)(blob + tid * 32)      = z;
        *(i32x4*)(blob + tid * 32 + 16) = z;
        if (cq == 0) colsum[bhh * 64 + w] = 0;
        return;
    }
    const int ZX = (int)rintf(*xzp);             // 128
    bool valid = (w >= 1 && w <= 56);
    const float* xb = x + (size_t)b * 128 * 3136 + (size_t)(hh - 1) * 56 +
                      (valid ? (w - 1) : 0);
    int csum = 0;
#pragma unroll
    for (int u = 0; u < 2; ++u) {
        union { char c[16]; i32x4 v; } uu;
#pragma unroll
        for (int j = 0; j < 16; ++j) {
            int c = cq * 32 + u * 16 + j;
            int val = valid ? ((int)xb[(size_t)c * 3136] - ZX) : 0;
            uu.c[j] = (char)val;
            csum += val;
        }
        *(i32x4*)(blob + w * 128 + ((cq * 32 + u * 16) ^ ((w & 7) << 4))) = uu.v;
    }
    ps[cq][w] = csum;
    __syncthreads();
    if (cq == 0)
        colsum[bhh * 64 + w] = ps[0][w] + ps[1][w] + ps[2][w] + ps[3][w];
}

// ---- main conv: barrier-free K-loop, reg-dbuf B, transposed-D ----
__global__ __launch_bounds__(256, 3)
void conv_kernel(const char* __restrict__ wt,
                 const char* __restrict__ xpi8,
                 const int* __restrict__ colsum,
                 const float* __restrict__ bias,
                 const float* __restrict__ Mp,
                 const float* __restrict__ wzp,
                 const float* __restrict__ yzp,
                 float* __restrict__ out) {
    __shared__ __align__(1024) char As[24576];     // A resident (3 row-blobs)
    __shared__ int s2row[64];

    const int tid = threadIdx.x;
    const int lane = tid & 63;
    const int wn = tid >> 6;                       // 0..3: 64-cout slice
    const int l15 = lane & 15, lg = lane >> 4;
    const int bx = blockIdx.x;                     // b*56 + h
    const int b = bx / 56;
    const int h = bx % 56;

    // ---- prologue: stage A (24KB) once; window colsum row ----
    const char* agbase = xpi8 + (size_t)(b * 58 + h) * 8192;
#pragma unroll
    for (int i = 0; i < 6; ++i)
        gload_lds16(agbase + i * 4096 + tid * 16, As + i * 4096 + tid * 16);
    if (tid < 64) {
        int s = 0;
        if (tid < 56) {
#pragma unroll
            for (int kh = 0; kh < 3; ++kh)
#pragma unroll
                for (int kw = 0; kw < 3; ++kw)
                    s += colsum[(b * 58 + h + kh) * 64 + tid + kw];
        }
        s2row[tid] = s;
    }

    // per-thread B panel offset (dense 1KB per fn-load)
    const char* bbase = wt + wn * 4096 + l15 * 64 + lg * 16;

    i32x4 acc[4][4];                               // [fn][fm] transposed-D
#pragma unroll
    for (int i = 0; i < 4; ++i)
#pragma unroll
        for (int j = 0; j < 4; ++j)
            acc[i][j] = (i32x4){0, 0, 0, 0};

    // issue step-0 B loads before the barrier (covered by prologue latency)
    i32x4 bcur[4], bnext[4];
#pragma unroll
    for (int fn = 0; fn < 4; ++fn)
        bcur[fn] = *(const i32x4*)(bbase + fn * 1024);

    __syncthreads();                               // the ONLY barrier

#pragma unroll
    for (int s = 0; s < 18; ++s) {                 // 9 taps x 2 cin-halves
        // prefetch step s+1's B panel into bnext (use is a full step away)
        if (s < 17) {
            const char* src = bbase + (size_t)(s + 1) * 16384;
#pragma unroll
            for (int fn = 0; fn < 4; ++fn)
                bnext[fn] = *(const i32x4*)(src + fn * 1024);
        }
        const int kh = (s >> 1) / 3, kw = (s >> 1) % 3, ch = s & 1;
        // A fragments from LDS (kw-shifted, swizzled)
        i32x4 afr[4];
#pragma unroll
        for (int fm = 0; fm < 4; ++fm) {
            int wv = fm * 16 + l15 + kw;
            int wc = wv > 63 ? 63 : wv;            // clamped lanes are dead outputs
            int ab = kh * 8192 + wc * 128 +
                     ((ch * 64 + lg * 16) ^ ((wc & 7) << 4));
            afr[fm] = *(const i32x4*)(As + ab);
        }
        // swapped operands: D[row=cout][col=m]
#pragma unroll
        for (int fn = 0; fn < 4; ++fn)
#pragma unroll
            for (int fm = 0; fm < 4; ++fm)
                acc[fn][fm] = __builtin_amdgcn_mfma_i32_16x16x64_i8(
                    bcur[fn], afr[fm], acc[fn][fm], 0, 0, 0);
#pragma unroll
        for (int fn = 0; fn < 4; ++fn)
            bcur[fn] = bnext[fn];
    }

    // ---- epilogue: +correction, requantize, ReLU, round; coalesced in m ----
    const float Mv  = *Mp;
    const float yzv = *yzp;
    const float CWf = 128.0f - *wzp;               // (128 - w_zero)
#pragma unroll
    for (int fn = 0; fn < 4; ++fn) {
#pragma unroll
        for (int reg = 0; reg < 4; ++reg) {
            const int cout = wn * 64 + fn * 16 + lg * 4 + reg;
            const float bv = bias[cout];
            const size_t rowb = ((size_t)(b * 256 + cout) * 56 + h) * 56;
#pragma unroll
            for (int fm = 0; fm < 4; ++fm) {
                int m = fm * 16 + l15;             // lane-contiguous
                if (m < 56) {
                    float af = (float)acc[fn][fm][reg] + CWf * (float)s2row[m];
                    float v = (af + bv) * Mv + yzv;
                    v = fmaxf(v, yzv);
                    out[rowb + m] = rintf(v);
                }
            }
        }
    }
}

extern "C" void kernel_launch(void* const* d_in, const int* in_sizes, int n_in,
                              void* d_out, int out_size, void* d_ws, size_t ws_size,
                              hipStream_t stream) {
    const float* x    = (const float*)d_in[0];
    const float* w    = (const float*)d_in[1];
    const float* bias = (const float*)d_in[2];
    const float* Mp   = (const float*)d_in[3];
    const float* xzp  = (const float*)d_in[4];
    const float* wzp  = (const float*)d_in[5];
    const float* yzp  = (const float*)d_in[6];
    float* out = (float*)d_out;

    char* wt     = (char*)d_ws;                          // 288 KB
    char* xpi8   = wt + WTI8_BYTES;                      // 15.2 MB
    int*  colsum = (int*)(xpi8 + XPI8_BYTES);            // 475 KB

    wprep_kernel<<<72, 256, 0, stream>>>(w, wt);
    xprep_kernel<<<32 * 58, 256, 0, stream>>>(x, xzp, xpi8, colsum);
    conv_kernel<<<32 * 56, 256, 0, stream>>>(wt, xpi8, colsum, bias, Mp, wzp, yzp, out);
}

// Round 15
// 78.674 us; speedup vs baseline: 1.4248x; 1.4248x over previous
//
#include <hip/hip_runtime.h>
#include <hip/hip_bf16.h>

// Quantized 3x3 conv via int8 implicit GEMM — R13 structure with block
// M=128 (2 output rows): halves the per-CU barrier-step count (the fixed
// ~600-1000 cyc/step stage-drain tax dominates; steps/CU 126 -> 63).
// B=32, Cin=128, Cout=256, H=W=56, pad=1. M=(b,h,w64), N=256, K=9x128.
//
// (x-xz)(w-wz) = xi*wi + (128-wz)*xi,  xi=x-128 (int8), wi=w-128 (int8);
// acc = i8gemm + (128-wz)*S,  S = window-sum of xi (pads contribute 0).
//
// xpi8 blob per (b,hh), 8KB: byte(w,c) = w*128 + (c ^ ((w&7)<<4)).
// wti8 blob per (r,ch), 16KB: byte(n,kl) = (n&63)*256 +
//   (((n>>6)*64 + kl) ^ (((n&63)&7)<<4)), kl in [0,64).
// Swizzles are involutions; conv stages with global_load_lds (LINEAR dest)
// and reads with the same XOR (rule #21).
//
// conv: 256 thr / 4 waves (1m x 4n), block tile 128m(2 h-rows) x 256n;
// per-wave 128m x 64n transposed-D (acc[fn][fm] : row=cout, col=m) ->
// coalesced stores (R13-proven). A = 4 row-blobs (32KB) resident; B dbuf
// 2x16KB staged per step; 18 steps x 32 MFMA/wave. LDS 64.5KB -> 2 blk/CU.

typedef __attribute__((ext_vector_type(4))) int   i32x4;
typedef __attribute__((ext_vector_type(4))) float f32x4;

#define WTI8_BYTES (18 * 16384)            // 294,912
#define XPI8_BYTES (32 * 58 * 8192)        // 15,204,352

__device__ __forceinline__ void gload_lds16(const void* g, void* l) {
    __builtin_amdgcn_global_load_lds(
        (const __attribute__((address_space(1))) void*)g,
        (__attribute__((address_space(3))) void*)l, 16, 0, 0);
}

// ---- weight prep: w[cout][cin][3][3] - 128 -> wti8 blobs (swizzle-baked) ----
__global__ void wprep_kernel(const float* __restrict__ w, char* __restrict__ wt) {
    int cidx = blockIdx.x * 256 + threadIdx.x;   // 16B chunk id, < 18432
    int blob = cidx >> 10;                       // r*2 + ch
    int e    = cidx & 1023;
    int byte0 = e * 16;
    int rr  = byte0 >> 8;                        // row 0..63
    int off = byte0 & 255;                       // 16-aligned
    int src = off ^ ((rr & 7) << 4);             // un-swizzle (16B-block safe)
    int q   = src >> 6;                          // n>>6
    int kl0 = src & 63;                          // 16-aligned
    int r = blob >> 1, ch = blob & 1;
    int n = q * 64 + rr;
    union { char c[16]; i32x4 v; } u;
#pragma unroll
    for (int j = 0; j < 16; ++j) {
        int cin = ch * 64 + kl0 + j;
        u.c[j] = (char)((int)w[(size_t)n * 1152 + cin * 9 + r] - 128);
    }
    *(i32x4*)(wt + (size_t)blob * 16384 + byte0) = u.v;
}

// ---- x prep: coalesced NCHW read -> swizzled padded NHWC int8 + colsum ----
__global__ void xprep_kernel(const float* __restrict__ x, const float* __restrict__ xzp,
                             char* __restrict__ xpi8, int* __restrict__ colsum) {
    int bhh = blockIdx.x;                        // b*58 + hh
    int b = bhh / 58, hh = bhh % 58;
    int tid = threadIdx.x;
    char* blob = xpi8 + (size_t)bhh * 8192;
    int w  = tid & 63;                           // padded col (lane = w: coalesced)
    int cq = tid >> 6;                           // 0..3, 32 cin each
    __shared__ int ps[4][64];
    if (hh == 0 || hh == 57) {
        i32x4 z = {0, 0, 0, 0};
        *(i32x4*)(blob + tid * 32)      = z;
        *(i32x4*)(blob + tid * 32 + 16) = z;
        if (cq == 0) colsum[bhh * 64 + w] = 0;
        return;
    }
    const int ZX = (int)rintf(*xzp);             // 128
    bool valid = (w >= 1 && w <= 56);
    const float* xb = x + (size_t)b * 128 * 3136 + (size_t)(hh - 1) * 56 +
                      (valid ? (w - 1) : 0);
    int csum = 0;
#pragma unroll
    for (int u = 0; u < 2; ++u) {
        union { char c[16]; i32x4 v; } uu;
#pragma unroll
        for (int j = 0; j < 16; ++j) {
            int c = cq * 32 + u * 16 + j;
            int val = valid ? ((int)xb[(size_t)c * 3136] - ZX) : 0;
            uu.c[j] = (char)val;
            csum += val;
        }
        *(i32x4*)(blob + w * 128 + ((cq * 32 + u * 16) ^ ((w & 7) << 4))) = uu.v;
    }
    ps[cq][w] = csum;
    __syncthreads();
    if (cq == 0)
        colsum[bhh * 64 + w] = ps[0][w] + ps[1][w] + ps[2][w] + ps[3][w];
}

// ---- main conv: int8 implicit GEMM, 2 h-rows/block, transposed-D ----
__global__ __launch_bounds__(256, 2)
void conv_kernel(const char* __restrict__ wt,
                 const char* __restrict__ xpi8,
                 const int* __restrict__ colsum,
                 const float* __restrict__ bias,
                 const float* __restrict__ Mp,
                 const float* __restrict__ wzp,
                 const float* __restrict__ yzp,
                 float* __restrict__ out) {
    __shared__ __align__(1024) char smem[65536];   // A 32KB + B dbuf 2x16KB
    __shared__ int s2row[2][64];
    char* As = smem;
    char* Bs = smem + 32768;

    const int tid = threadIdx.x;
    const int lane = tid & 63;
    const int wn = tid >> 6;                       // 0..3: 64-cout slice
    const int l15 = lane & 15, lg = lane >> 4;
    const int bx = blockIdx.x;                     // b*28 + hp
    const int b = bx / 28;
    const int h0 = (bx % 28) * 2;                  // 2 output rows per block

    // ---- prologue: A = 4 row-blobs (32KB); B stage 0 (16KB); S2 rows ----
    const char* agbase = xpi8 + (size_t)(b * 58 + h0) * 8192;
#pragma unroll
    for (int i = 0; i < 8; ++i)
        gload_lds16(agbase + i * 4096 + tid * 16, As + i * 4096 + tid * 16);
#pragma unroll
    for (int i = 0; i < 4; ++i)
        gload_lds16(wt + i * 4096 + tid * 16, Bs + i * 4096 + tid * 16);
    if (tid < 128) {
        int row = tid >> 6, m = tid & 63;
        int s = 0;
        if (m < 56) {
#pragma unroll
            for (int kh = 0; kh < 3; ++kh)
#pragma unroll
                for (int kw = 0; kw < 3; ++kw)
                    s += colsum[(b * 58 + h0 + row + kh) * 64 + m + kw];
        }
        s2row[row][m] = s;
    }

    i32x4 acc[4][8];                               // [fn][fm]: row=cout, col=m
#pragma unroll
    for (int i = 0; i < 4; ++i)
#pragma unroll
        for (int j = 0; j < 8; ++j)
            acc[i][j] = (i32x4){0, 0, 0, 0};

    __syncthreads();                               // A + B0 + s2row ready

#pragma unroll
    for (int s = 0; s < 18; ++s) {                 // 9 taps x 2 cin-halves
        // prefetch next B blob into the other slot (issue-early, proven)
        if (s < 17) {
            const char* src = wt + (size_t)(s + 1) * 16384;
            char* dst = Bs + ((s + 1) & 1) * 16384;
#pragma unroll
            for (int i = 0; i < 4; ++i)
                gload_lds16(src + i * 4096 + tid * 16, dst + i * 4096 + tid * 16);
        }
        const int kh = (s >> 1) / 3, kw = (s >> 1) % 3, ch = s & 1;
        // B fragments (w): free = l15, k-chunk = lg
        i32x4 bfr[4];
#pragma unroll
        for (int fn = 0; fn < 4; ++fn) {
            int rr = fn * 16 + l15;
            int bb = (s & 1) * 16384 + rr * 256 +
                     ((wn * 64 + lg * 16) ^ ((rr & 7) << 4));
            bfr[fn] = *(const i32x4*)(Bs + bb);
        }
        // A fragments: 8 = 2 h-rows x 4 w-quarters (kw-shifted, swizzled)
        i32x4 afr[8];
#pragma unroll
        for (int fm = 0; fm < 8; ++fm) {
            int rowoff = fm >> 2;                  // 0..1: output row
            int wv = (fm & 3) * 16 + l15 + kw;
            int wc = wv > 63 ? 63 : wv;            // clamped lanes are dead outputs
            int ab = (kh + rowoff) * 8192 + wc * 128 +
                     ((ch * 64 + lg * 16) ^ ((wc & 7) << 4));
            afr[fm] = *(const i32x4*)(As + ab);
        }
        // swapped operands: D[row=cout][col=m]
#pragma unroll
        for (int fn = 0; fn < 4; ++fn)
#pragma unroll
            for (int fm = 0; fm < 8; ++fm)
                acc[fn][fm] = __builtin_amdgcn_mfma_i32_16x16x64_i8(
                    bfr[fn], afr[fm], acc[fn][fm], 0, 0, 0);
        __syncthreads();                           // drain prefetch + WAR guard
    }

    // ---- epilogue: +correction, requantize, ReLU, round; coalesced in m ----
    const float Mv  = *Mp;
    const float yzv = *yzp;
    const float CWf = 128.0f - *wzp;               // (128 - w_zero)
#pragma unroll
    for (int fn = 0; fn < 4; ++fn) {
#pragma unroll
        for (int reg = 0; reg < 4; ++reg) {
            const int cout = wn * 64 + fn * 16 + lg * 4 + reg;
            const float bv = bias[cout];
#pragma unroll
            for (int fm = 0; fm < 8; ++fm) {
                const int rowoff = fm >> 2;
                const int m = (fm & 3) * 16 + l15; // lane-contiguous
                if (m < 56) {
                    const size_t rowb =
                        ((size_t)(b * 256 + cout) * 56 + h0 + rowoff) * 56;
                    float af = (float)acc[fn][fm][reg] +
                               CWf * (float)s2row[rowoff][m];
                    float v = (af + bv) * Mv + yzv;
                    v = fmaxf(v, yzv);
                    out[rowb + m] = rintf(v);
                }
            }
        }
    }
}

extern "C" void kernel_launch(void* const* d_in, const int* in_sizes, int n_in,
                              void* d_out, int out_size, void* d_ws, size_t ws_size,
                              hipStream_t stream) {
    const float* x    = (const float*)d_in[0];
    const float* w    = (const float*)d_in[1];
    const float* bias = (const float*)d_in[2];
    const float* Mp   = (const float*)d_in[3];
    const float* xzp  = (const float*)d_in[4];
    const float* wzp  = (const float*)d_in[5];
    const float* yzp  = (const float*)d_in[6];
    float* out = (float*)d_out;

    char* wt     = (char*)d_ws;                          // 288 KB
    char* xpi8   = wt + WTI8_BYTES;                      // 15.2 MB
    int*  colsum = (int*)(xpi8 + XPI8_BYTES);            // 475 KB

    wprep_kernel<<<72, 256, 0, stream>>>(w, wt);
    xprep_kernel<<<32 * 58, 256, 0, stream>>>(x, xzp, xpi8, colsum);
    conv_kernel<<<32 * 28, 256, 0, stream>>>(wt, xpi8, colsum, bias, Mp, wzp, yzp, out);
}